// Round 1
// baseline (2914.520 us; speedup 1.0000x reference)
//
#include <hip/hip_runtime.h>
#include <cmath>

// Problem dims (fixed by setup_inputs)
#define B_SZ  32
#define LATD  64
#define HU    96     // LSTM units
#define G4    384    // 4*H
#define T_LEN 512
#define VOC   10000

// Dense/softmax tiling
#define VCH   128    // v-columns per chunk
#define RT    32     // rows per block
#define APAD  100    // padded LDS stride for A tile (bank-conflict-free, 16B aligned)

// ---------------- Kernel 1: zp + LSTM recurrence ----------------
// One block per batch element. Thread t (0..383) owns gate column t:
// U[:,t] in registers, h broadcast from LDS. 2 barriers per step.
__global__ __launch_bounds__(384) void lstm_seq(const float* __restrict__ z,
                                                const float* __restrict__ W,
                                                const float* __restrict__ U,
                                                const float* __restrict__ bias,
                                                float* __restrict__ hs) {
  __shared__ float h_lds[HU];
  __shared__ float g_lds[G4];
  __shared__ float z_lds[LATD];
  const int t  = threadIdx.x;
  const int bb = blockIdx.x;

  if (t < LATD) z_lds[t] = z[bb * LATD + t];
  if (t < HU)   h_lds[t] = 0.f;
  __syncthreads();

  // U column into registers (coalesced across t)
  float u[HU];
#pragma unroll
  for (int k = 0; k < HU; ++k) u[k] = U[k * G4 + t];

  // zp = b[t] + sum_k z[bb,k] * W[k,t]  (computed once, reused all T steps)
  float zp = bias[t];
#pragma unroll
  for (int k = 0; k < LATD; ++k) zp += z_lds[k] * W[k * G4 + t];

  float c = 0.f;
  for (int s = 0; s < T_LEN; ++s) {
    float g = zp;
#pragma unroll
    for (int k = 0; k < HU; ++k) g += h_lds[k] * u[k];
    g_lds[t] = g;
    __syncthreads();
    if (t < HU) {
      float gi = g_lds[t];
      float gf = g_lds[t + HU];
      float gc = g_lds[t + 2 * HU];
      float go = g_lds[t + 3 * HU];
      float i_ = 1.f / (1.f + expf(-gi));
      float f_ = 1.f / (1.f + expf(-gf));
      float cb = tanhf(gc);
      float o_ = 1.f / (1.f + expf(-go));
      c = f_ * c + i_ * cb;
      float h = o_ * tanhf(c);
      h_lds[t] = h;
      hs[((size_t)bb * T_LEN + s) * HU + t] = h;
    }
    __syncthreads();
  }
}

// ---------------- Kernel 2: dense + softmax (2-pass recompute) ----------------
// Each block owns RT=32 consecutive (b,t) rows and ALL 10000 vocab columns.
// Pass 0: GEMM -> sum of exp(logit) per row (no max subtraction; logits bounded).
// Pass 1: GEMM again -> out = exp(logit) * invS.  Wd stays L2/L3-hot.
// Thread map: row = tid>>3 (0..31), colgroup = tid&7; thread covers 16
// contiguous columns [cg*16, cg*16+16) of each 128-wide chunk.
__global__ __launch_bounds__(256) void dense_softmax(const float* __restrict__ hs,
                                                     const float* __restrict__ Wd,
                                                     const float* __restrict__ bd,
                                                     float* __restrict__ out) {
  __shared__ float Al[RT * APAD];   // 12.8 KB
  __shared__ float Bl[HU * VCH];    // 49.2 KB
  const int tid = threadIdx.x;
  const int R0  = blockIdx.x * RT;
  const int row = tid >> 3;
  const int cg  = tid & 7;

  // Stage A tile (32 rows x 96) once; padded stride 100 (400B, 16B aligned)
  for (int i4 = tid; i4 < RT * (HU / 4); i4 += 256) {
    int r = i4 / (HU / 4), k4 = i4 % (HU / 4);
    float4 v = *(const float4*)(hs + ((size_t)(R0 + r)) * HU + k4 * 4);
    *(float4*)(&Al[r * APAD + k4 * 4]) = v;
  }

  float s_part = 0.f;
  float invS   = 0.f;
  const int NCH = (VOC + VCH - 1) / VCH;  // 79

  for (int pass = 0; pass < 2; ++pass) {
    for (int ch = 0; ch < NCH; ++ch) {
      const int v0 = ch * VCH;
      __syncthreads();  // protect previous chunk's Bl reads (also covers Al 1st iter)
      // Stage B chunk: 96 x 128 floats = 3072 float4 / 256 thr = 12 each
      for (int i4 = tid; i4 < HU * (VCH / 4); i4 += 256) {
        int k  = i4 >> 5;        // VCH/4 == 32
        int c4 = i4 & 31;
        int v  = v0 + c4 * 4;
        float4 val = make_float4(0.f, 0.f, 0.f, 0.f);
        if (v + 3 < VOC) val = *(const float4*)(Wd + (size_t)k * VOC + v);
        *(float4*)(&Bl[k * VCH + c4 * 4]) = val;
      }
      __syncthreads();

      float acc[16];
#pragma unroll
      for (int j = 0; j < 16; ++j) acc[j] = 0.f;
      const float* ap = &Al[row * APAD];
      const float* bp = &Bl[cg * 16];
#pragma unroll 4
      for (int k = 0; k < HU; ++k) {
        float a = ap[k];
#pragma unroll
        for (int j = 0; j < 16; ++j) acc[j] += a * bp[k * VCH + j];
      }

      const int colbase = v0 + cg * 16;
      if (pass == 0) {
#pragma unroll
        for (int j = 0; j < 16; ++j) {
          int v = colbase + j;
          if (v < VOC) s_part += expf(acc[j] + bd[v]);
        }
      } else {
        float* op = out + ((size_t)(R0 + row)) * VOC + colbase;
#pragma unroll
        for (int j = 0; j < 16; ++j) {
          int v = colbase + j;
          if (v < VOC) op[j] = expf(acc[j] + bd[v]) * invS;
        }
      }
    }
    if (pass == 0) {
      // 8 threads (lanes 8r..8r+7) share a row: butterfly reduce in-wave
      float s = s_part;
      s += __shfl_xor(s, 1);
      s += __shfl_xor(s, 2);
      s += __shfl_xor(s, 4);
      invS = 1.f / s;
    }
  }
}

extern "C" void kernel_launch(void* const* d_in, const int* in_sizes, int n_in,
                              void* d_out, int out_size, void* d_ws, size_t ws_size,
                              hipStream_t stream) {
  const float* z  = (const float*)d_in[0];
  const float* W  = (const float*)d_in[1];
  const float* U  = (const float*)d_in[2];
  const float* b  = (const float*)d_in[3];
  const float* Wd = (const float*)d_in[4];
  const float* bd = (const float*)d_in[5];
  // d_in[6] = seq_len (known fixed at 512)
  float* out = (float*)d_out;
  float* hs  = (float*)d_ws;  // 32*512*96 f32 = 6.3 MB

  lstm_seq<<<B_SZ, 384, 0, stream>>>(z, W, U, b, hs);
  dense_softmax<<<(B_SZ * T_LEN) / RT, 256, 0, stream>>>(hs, Wd, bd, out);
}

// Round 2
// 721.310 us; speedup vs baseline: 4.0406x; 4.0406x over previous
//
#include <hip/hip_runtime.h>
#include <cmath>

// Problem dims (fixed by setup_inputs)
#define B_SZ  32
#define LATD  64
#define HU    96     // LSTM units
#define G4    384    // 4*H
#define T_LEN 512
#define VOC   10000
#define NROWS (B_SZ * T_LEN)   // 16384

// Dense tiling: 256 blocks x 8 waves; block owns 64 rows x all cols.
#define RT2    64
#define NCHK   40     // ceil(10000 / 256)
#define C16PAD 640    // 16-col groups incl. zero pad (625 real)

typedef __attribute__((ext_vector_type(8))) short bf16x8;
typedef __attribute__((ext_vector_type(4))) float f32x4;

__device__ __forceinline__ unsigned short f2bf(float x) {
  unsigned u = __float_as_uint(x);
  u += 0x7fffu + ((u >> 16) & 1u);   // round-to-nearest-even
  return (unsigned short)(u >> 16);
}
__device__ __forceinline__ float fsig(float x) {
  return __builtin_amdgcn_rcpf(1.f + __expf(-x));
}
__device__ __forceinline__ float ftanh(float x) {
  return 1.f - 2.f * __builtin_amdgcn_rcpf(1.f + __expf(2.f * x));
}

// ---------------- Kernel 0: pack Wd into bf16 MFMA-B-fragment order ----------
// Element j of lane l's 16B chunk for (c16, K16) = Wd[K16*32 + (l>>4)*8 + j]
//                                                   [c16*16 + (l&15)]
// Zero-filled for col >= VOC (pad region c16 in [625,640)).
__global__ __launch_bounds__(256) void pack_wd(const float* __restrict__ Wd,
                                               uint4* __restrict__ Bp) {
  const int gid = blockIdx.x * 256 + threadIdx.x;
  if (gid >= C16PAD * 3 * 64) return;
  const int l   = gid & 63;
  const int K16 = (gid >> 6) % 3;
  const int c16 = gid / 192;
  const int col = c16 * 16 + (l & 15);
  const int k0  = K16 * 32 + (l >> 4) * 8;
  unsigned w[4];
#pragma unroll
  for (int jj = 0; jj < 4; ++jj) {
    float x0 = 0.f, x1 = 0.f;
    if (col < VOC) {
      x0 = Wd[(size_t)(k0 + 2 * jj) * VOC + col];
      x1 = Wd[(size_t)(k0 + 2 * jj + 1) * VOC + col];
    }
    w[jj] = (unsigned)f2bf(x0) | ((unsigned)f2bf(x1) << 16);
  }
  Bp[gid] = make_uint4(w[0], w[1], w[2], w[3]);
}

// ---------------- Kernel 1: zp + LSTM recurrence (1 barrier/step) -----------
// 6 waves. Lane quad (4 lanes) owns one hidden unit: gate = l&3, unit
// j = wave*16 + (l>>2), U column = gate*96 + j. Gate values exchanged
// in-wave via shfl; h double-buffered in LDS.
__global__ __launch_bounds__(384) void lstm_seq(const float* __restrict__ z,
                                                const float* __restrict__ W,
                                                const float* __restrict__ U,
                                                const float* __restrict__ bias,
                                                unsigned short* __restrict__ hsb) {
  __shared__ float h_lds[2][HU];
  __shared__ float z_lds[LATD];
  const int t    = threadIdx.x;
  const int bb   = blockIdx.x;
  const int l    = t & 63;
  const int wv   = t >> 6;
  const int j    = wv * 16 + (l >> 2);
  const int gate = l & 3;
  const int col  = gate * HU + j;
  const int base = l & ~3;

  if (t < LATD) z_lds[t] = z[bb * LATD + t];
  if (t < HU)   h_lds[0][t] = 0.f;
  __syncthreads();

  // U column (as float2 pairs over k) into registers
  float2 u2[HU / 2];
#pragma unroll
  for (int k = 0; k < HU / 2; ++k) {
    u2[k].x = U[(size_t)(2 * k) * G4 + col];
    u2[k].y = U[(size_t)(2 * k + 1) * G4 + col];
  }
  // zp = b[col] + z . W[:,col], reused across all T steps
  float zp = bias[col];
#pragma unroll
  for (int k = 0; k < LATD; ++k) zp += z_lds[k] * W[(size_t)k * G4 + col];

  float c = 0.f;
  int p = 0;
  for (int s = 0; s < T_LEN; ++s) {
    const float2* hp = (const float2*)h_lds[p];
    float ax = 0.f, ay = 0.f;
#pragma unroll
    for (int k = 0; k < HU / 2; ++k) {
      float2 hv = hp[k];
      ax = fmaf(hv.x, u2[k].x, ax);
      ay = fmaf(hv.y, u2[k].y, ay);
    }
    const float g  = zp + ax + ay;
    const float gi = __shfl(g, base);
    const float gf = __shfl(g, base + 1);
    const float gc = __shfl(g, base + 2);
    const float go = __shfl(g, base + 3);
    const float i_ = fsig(gi);
    const float f_ = fsig(gf);
    const float cb = ftanh(gc);
    const float o_ = fsig(go);
    c = f_ * c + i_ * cb;
    const float h = o_ * ftanh(c);
    if (gate == 0) {
      h_lds[p ^ 1][j] = h;
      hsb[((size_t)bb * T_LEN + s) * HU + j] = f2bf(h);
    }
    __syncthreads();
    p ^= 1;
  }
}

// ---------------- Kernel 2: dense + softmax, MFMA, 2-pass recompute ---------
// 8 waves: roww = wv>>2 (32-row half), colw = wv&3 (64-col slice per chunk).
// A-fragments (rows) hoisted to registers once; B fragments loaded straight
// from packed global (coalesced 16B/lane, L2-resident). Pass 0 accumulates
// sum(exp(logit)) per row; pass 1 writes exp(logit)*invS.
__global__ __launch_bounds__(512) void dense_softmax_mfma(
    const unsigned short* __restrict__ hsb, const bf16x8* __restrict__ Bp,
    const float* __restrict__ bd, float* __restrict__ out) {
  __shared__ __align__(16) unsigned short Al[RT2 * HU];  // 12 KB
  __shared__ float srow[4][RT2];
  const int tid  = threadIdx.x;
  const int l    = tid & 63, wv = tid >> 6;
  const int roww = wv >> 2, colw = wv & 3;
  const int l15  = l & 15, l4 = l >> 4;
  const int R0   = blockIdx.x * RT2;

  // stage A rows (64 x 96 bf16 = 12 KB), then fragments -> registers
  {
    const uint4* src = (const uint4*)(hsb + (size_t)R0 * HU);
    uint4* dst = (uint4*)Al;
    for (int i = tid; i < RT2 * HU / 8; i += 512) dst[i] = src[i];
  }
  __syncthreads();

  bf16x8 afr[2][3];
#pragma unroll
  for (int r16 = 0; r16 < 2; ++r16)
#pragma unroll
    for (int K16 = 0; K16 < 3; ++K16)
      afr[r16][K16] =
          *(const bf16x8*)(Al + (roww * 32 + r16 * 16 + l15) * HU + K16 * 32 + l4 * 8);

  float ssum[2][4];
#pragma unroll
  for (int r16 = 0; r16 < 2; ++r16)
#pragma unroll
    for (int q = 0; q < 4; ++q) ssum[r16][q] = 0.f;
  float sinvr[2][4];

  for (int pass = 0; pass < 2; ++pass) {
    for (int ch = 0; ch < NCHK; ++ch) {
#pragma unroll
      for (int cf = 0; cf < 4; ++cf) {
        const int c16 = ch * 16 + colw * 4 + cf;
        const bf16x8* bp = Bp + (size_t)c16 * 192 + l;  // 3*64 frags per c16
        bf16x8 bfr[3];
#pragma unroll
        for (int K16 = 0; K16 < 3; ++K16) bfr[K16] = bp[K16 * 64];
        f32x4 acc0 = {0.f, 0.f, 0.f, 0.f};
        f32x4 acc1 = {0.f, 0.f, 0.f, 0.f};
#pragma unroll
        for (int K16 = 0; K16 < 3; ++K16) {
          acc0 = __builtin_amdgcn_mfma_f32_16x16x32_bf16(afr[0][K16], bfr[K16], acc0, 0, 0, 0);
          acc1 = __builtin_amdgcn_mfma_f32_16x16x32_bf16(afr[1][K16], bfr[K16], acc1, 0, 0, 0);
        }
        const int col = c16 * 16 + l15;
        const bool cv = col < VOC;
        const float bdv = cv ? bd[col] : 0.f;
        if (pass == 0) {
          if (cv) {
#pragma unroll
            for (int q = 0; q < 4; ++q) {
              ssum[0][q] += __expf(acc0[q] + bdv);
              ssum[1][q] += __expf(acc1[q] + bdv);
            }
          }
        } else if (cv) {
#pragma unroll
          for (int q = 0; q < 4; ++q) {
            const int r0 = R0 + roww * 32 + l4 * 4 + q;
            out[(size_t)r0 * VOC + col]        = __expf(acc0[q] + bdv) * sinvr[0][q];
            out[(size_t)(r0 + 16) * VOC + col] = __expf(acc1[q] + bdv) * sinvr[1][q];
          }
        }
      }
    }
    if (pass == 0) {
      // reduce over the 16 lanes (l&15) sharing the same row set
#pragma unroll
      for (int r16 = 0; r16 < 2; ++r16)
#pragma unroll
        for (int q = 0; q < 4; ++q) {
          float v = ssum[r16][q];
          v += __shfl_xor(v, 1);
          v += __shfl_xor(v, 2);
          v += __shfl_xor(v, 4);
          v += __shfl_xor(v, 8);
          ssum[r16][q] = v;
        }
      if (l15 == 0) {
#pragma unroll
        for (int r16 = 0; r16 < 2; ++r16)
#pragma unroll
          for (int q = 0; q < 4; ++q)
            srow[colw][roww * 32 + r16 * 16 + l4 * 4 + q] = ssum[r16][q];
      }
      __syncthreads();
#pragma unroll
      for (int r16 = 0; r16 < 2; ++r16)
#pragma unroll
        for (int q = 0; q < 4; ++q) {
          const int r = roww * 32 + r16 * 16 + l4 * 4 + q;
          sinvr[r16][q] = 1.f / (srow[0][r] + srow[1][r] + srow[2][r] + srow[3][r]);
        }
    }
  }
}

extern "C" void kernel_launch(void* const* d_in, const int* in_sizes, int n_in,
                              void* d_out, int out_size, void* d_ws, size_t ws_size,
                              hipStream_t stream) {
  const float* z  = (const float*)d_in[0];
  const float* W  = (const float*)d_in[1];
  const float* U  = (const float*)d_in[2];
  const float* b  = (const float*)d_in[3];
  const float* Wd = (const float*)d_in[4];
  const float* bd = (const float*)d_in[5];
  float* out = (float*)d_out;

  unsigned short* hsb = (unsigned short*)d_ws;                       // 3.15 MB bf16 hs
  uint4* Bp = (uint4*)((char*)d_ws + (size_t)NROWS * HU * 2);        // 1.97 MB packed Wd

  pack_wd<<<(C16PAD * 3 * 64 + 255) / 256, 256, 0, stream>>>(Wd, Bp);
  lstm_seq<<<B_SZ, 384, 0, stream>>>(z, W, U, b, hsb);
  dense_softmax_mfma<<<NROWS / RT2, 512, 0, stream>>>(hsb, (const bf16x8*)Bp, bd, out);
}

// Round 3
// 715.492 us; speedup vs baseline: 4.0734x; 1.0081x over previous
//
#include <hip/hip_runtime.h>
#include <cmath>

// Problem dims (fixed by setup_inputs)
#define B_SZ  32
#define LATD  64
#define HU    96
#define G4    384
#define T_LEN 512
#define VOC   10000
#define NROWS (B_SZ * T_LEN)        // 16384
#define NC16  625                   // 10000/16 exactly
#define NSPLIT 5
#define C16S  125                   // c16 tiles per split
#define RBLK  32                    // rows per dense block
#define PPR   (NSPLIT * 2)          // partials per row

typedef __attribute__((ext_vector_type(8))) short bf16x8;
typedef __attribute__((ext_vector_type(4))) float f32x4;

__device__ __forceinline__ unsigned short f2bf(float x) {
  unsigned u = __float_as_uint(x);
  u += 0x7fffu + ((u >> 16) & 1u);   // RNE
  return (unsigned short)(u >> 16);
}
__device__ __forceinline__ float fsig(float x) {
  return __builtin_amdgcn_rcpf(1.f + __expf(-x));
}
__device__ __forceinline__ float ftanh(float x) {
  return 1.f - 2.f * __builtin_amdgcn_rcpf(1.f + __expf(2.f * x));
}

// ---------------- Kernel 0: pack Wd into bf16 MFMA-B-fragment order ----------
// Lane chunk for (c16,K16,l): element j = Wd[K16*32+(l>>4)*8+j][c16*16+(l&15)]
__global__ __launch_bounds__(256) void pack_wd(const float* __restrict__ Wd,
                                               uint4* __restrict__ Bp) {
  const int gid = blockIdx.x * 256 + threadIdx.x;
  if (gid >= NC16 * 3 * 64) return;
  const int l   = gid & 63;
  const int K16 = (gid >> 6) % 3;
  const int c16 = gid / 192;
  const int col = c16 * 16 + (l & 15);
  const int k0  = K16 * 32 + (l >> 4) * 8;
  unsigned w[4];
#pragma unroll
  for (int jj = 0; jj < 4; ++jj) {
    float x0 = Wd[(size_t)(k0 + 2 * jj) * VOC + col];
    float x1 = Wd[(size_t)(k0 + 2 * jj + 1) * VOC + col];
    w[jj] = (unsigned)f2bf(x0) | ((unsigned)f2bf(x1) << 16);
  }
  Bp[gid] = make_uint4(w[0], w[1], w[2], w[3]);
}

// ---------------- Kernel 1: zp + LSTM recurrence ----------------------------
// 192 threads (3 waves), thread t owns gate-columns {t, t+192}:
//   t <  96: (i, cbar) of unit t      t >= 96: (f, o) of unit t-96
// h kept as bf16 pairs in LDS (12 uniform b128 reads/lane/step); U columns in
// f32 registers; (f,o) cross to the unit owner via a float2 LDS slot.
__global__ __launch_bounds__(192) void lstm_seq(const float* __restrict__ z,
                                                const float* __restrict__ W,
                                                const float* __restrict__ U,
                                                const float* __restrict__ bias,
                                                unsigned short* __restrict__ hsb) {
  __shared__ unsigned int h_lds[2][HU / 2];  // bf16 pairs, double-buffered
  __shared__ float2 ex[HU];                  // (sig(f), sig(o)) per unit
  __shared__ float z_lds[LATD];
  const int t  = threadIdx.x;
  const int bb = blockIdx.x;
  const int c0 = t, c1 = t + 192;

  if (t < LATD)   z_lds[t] = z[bb * LATD + t];
  if (t < HU / 2) h_lds[0][t] = 0u;
  __syncthreads();

  // U columns, f32 in registers (static indices only)
  float uf0[HU], uf1[HU];
#pragma unroll
  for (int k = 0; k < HU; ++k) {
    uf0[k] = U[(size_t)k * G4 + c0];
    uf1[k] = U[(size_t)k * G4 + c1];
  }
  // zp = b + z.W column (reused all steps)
  float zp0 = bias[c0], zp1 = bias[c1];
#pragma unroll
  for (int k = 0; k < LATD; ++k) {
    zp0 = fmaf(z_lds[k], W[(size_t)k * G4 + c0], zp0);
    zp1 = fmaf(z_lds[k], W[(size_t)k * G4 + c1], zp1);
  }

  float c_st = 0.f;
  int p = 0;
  for (int s = 0; s < T_LEN; ++s) {
    const uint4* hp = (const uint4*)h_lds[p];
    float a00 = 0.f, a01 = 0.f, a02 = 0.f, a03 = 0.f;
    float a10 = 0.f, a11 = 0.f, a12 = 0.f, a13 = 0.f;
#pragma unroll
    for (int w4 = 0; w4 < 12; ++w4) {
      const uint4 hv = hp[w4];
      const int k0 = 8 * w4;
      {
        float hl = __uint_as_float(hv.x << 16);
        float hh = __uint_as_float(hv.x & 0xffff0000u);
        a00 = fmaf(hl, uf0[k0 + 0], a00); a00 = fmaf(hh, uf0[k0 + 1], a00);
        a10 = fmaf(hl, uf1[k0 + 0], a10); a10 = fmaf(hh, uf1[k0 + 1], a10);
      }
      {
        float hl = __uint_as_float(hv.y << 16);
        float hh = __uint_as_float(hv.y & 0xffff0000u);
        a01 = fmaf(hl, uf0[k0 + 2], a01); a01 = fmaf(hh, uf0[k0 + 3], a01);
        a11 = fmaf(hl, uf1[k0 + 2], a11); a11 = fmaf(hh, uf1[k0 + 3], a11);
      }
      {
        float hl = __uint_as_float(hv.z << 16);
        float hh = __uint_as_float(hv.z & 0xffff0000u);
        a02 = fmaf(hl, uf0[k0 + 4], a02); a02 = fmaf(hh, uf0[k0 + 5], a02);
        a12 = fmaf(hl, uf1[k0 + 4], a12); a12 = fmaf(hh, uf1[k0 + 5], a12);
      }
      {
        float hl = __uint_as_float(hv.w << 16);
        float hh = __uint_as_float(hv.w & 0xffff0000u);
        a03 = fmaf(hl, uf0[k0 + 6], a03); a03 = fmaf(hh, uf0[k0 + 7], a03);
        a13 = fmaf(hl, uf1[k0 + 6], a13); a13 = fmaf(hh, uf1[k0 + 7], a13);
      }
    }
    const float g0 = zp0 + ((a00 + a01) + (a02 + a03));
    const float g1 = zp1 + ((a10 + a11) + (a12 + a13));

    if (t >= HU) ex[t - HU] = make_float2(fsig(g0), fsig(g1));  // f, o
    __syncthreads();
    if (t < HU) {
      const float i_ = fsig(g0);
      const float cb = ftanh(g1);
      const float2 fo = ex[t];
      c_st = fo.x * c_st + i_ * cb;
      const float h = fo.y * ftanh(c_st);
      const unsigned short hb = f2bf(h);
      ((unsigned short*)h_lds[p ^ 1])[t] = hb;
      hsb[((size_t)bb * T_LEN + s) * HU + t] = hb;
    }
    __syncthreads();
    p ^= 1;
  }
}

// ---------------- Kernels 2/4: dense GEMM passes ----------------------------
// Grid: 512 row-blocks x NSPLIT v-splits (bid: s=bid/512, rb=bid%512).
// 4 waves: r16 = wv&1 (16-row tile), cg = wv>>1 (odd/even c16 within split).
// PASS 0: partial sum(exp(logit)) -> part[row][s*2+cg].
// PASS 1: recompute logits (identical MFMA sequence) -> nontemporal out.
template <int PASS>
__global__ __launch_bounds__(256) void dense_pass(
    const unsigned short* __restrict__ hsb, const bf16x8* __restrict__ Bp,
    const float* __restrict__ bd, const float* __restrict__ invS,
    float* __restrict__ outp) {
  __shared__ __align__(16) unsigned short Al[RBLK * HU];  // 6 KB
  const int tid = threadIdx.x;
  const int l = tid & 63, wv = tid >> 6;
  const int r16 = wv & 1, cg = wv >> 1;
  const int l15 = l & 15, l4 = l >> 4;
  const int s = blockIdx.x / 512, rb = blockIdx.x % 512;
  const int R0 = rb * RBLK;

  {
    const uint4* src = (const uint4*)(hsb + (size_t)R0 * HU);
    uint4* dst = (uint4*)Al;
    for (int i = tid; i < RBLK * HU / 8; i += 256) dst[i] = src[i];
  }
  __syncthreads();

  bf16x8 afr[3];
#pragma unroll
  for (int K16 = 0; K16 < 3; ++K16)
    afr[K16] = *(const bf16x8*)(Al + (r16 * 16 + l15) * HU + K16 * 32 + l4 * 8);

  float iv[4];
  float ssum[4] = {0.f, 0.f, 0.f, 0.f};
  if (PASS == 1) {
#pragma unroll
    for (int q = 0; q < 4; ++q) iv[q] = invS[R0 + r16 * 16 + l4 * 4 + q];
  }

  const int cbase = s * C16S;
  for (int i = cg; i < C16S; i += 2) {
    const int c16 = cbase + i;
    const bf16x8* bp = Bp + (size_t)c16 * 192 + l;
    const bf16x8 b0 = bp[0], b1 = bp[64], b2 = bp[128];
    f32x4 acc = {0.f, 0.f, 0.f, 0.f};
    acc = __builtin_amdgcn_mfma_f32_16x16x32_bf16(afr[0], b0, acc, 0, 0, 0);
    acc = __builtin_amdgcn_mfma_f32_16x16x32_bf16(afr[1], b1, acc, 0, 0, 0);
    acc = __builtin_amdgcn_mfma_f32_16x16x32_bf16(afr[2], b2, acc, 0, 0, 0);
    const int col = c16 * 16 + l15;
    const float bdv = bd[col];
    if (PASS == 0) {
#pragma unroll
      for (int q = 0; q < 4; ++q) ssum[q] += __expf(acc[q] + bdv);
    } else {
#pragma unroll
      for (int q = 0; q < 4; ++q) {
        const size_t r = (size_t)(R0 + r16 * 16 + l4 * 4 + q);
        __builtin_nontemporal_store(__expf(acc[q] + bdv) * iv[q],
                                    outp + r * VOC + col);
      }
    }
  }

  if (PASS == 0) {
#pragma unroll
    for (int q = 0; q < 4; ++q) {
      float v = ssum[q];
      v += __shfl_xor(v, 1);
      v += __shfl_xor(v, 2);
      v += __shfl_xor(v, 4);
      v += __shfl_xor(v, 8);
      ssum[q] = v;
    }
    if (l15 == 0) {
#pragma unroll
      for (int q = 0; q < 4; ++q)
        outp[(size_t)(R0 + r16 * 16 + l4 * 4 + q) * PPR + s * 2 + cg] = ssum[q];
    }
  }
}

// ---------------- Kernel 3: reduce partials -> invS -------------------------
__global__ __launch_bounds__(256) void reduce_inv(const float* __restrict__ part,
                                                  float* __restrict__ invS) {
  const int r = blockIdx.x * 256 + threadIdx.x;
  if (r < NROWS) {
    float s = 0.f;
#pragma unroll
    for (int i = 0; i < PPR; ++i) s += part[(size_t)r * PPR + i];
    invS[r] = 1.f / s;
  }
}

extern "C" void kernel_launch(void* const* d_in, const int* in_sizes, int n_in,
                              void* d_out, int out_size, void* d_ws, size_t ws_size,
                              hipStream_t stream) {
  const float* z  = (const float*)d_in[0];
  const float* W  = (const float*)d_in[1];
  const float* U  = (const float*)d_in[2];
  const float* b  = (const float*)d_in[3];
  const float* Wd = (const float*)d_in[4];
  const float* bd = (const float*)d_in[5];
  float* out = (float*)d_out;

  char* ws = (char*)d_ws;
  unsigned short* hsb = (unsigned short*)ws;                 // 3,145,728 B
  uint4* Bp   = (uint4*)(ws + 3145728);                      // 1,920,000 B
  float* part = (float*)(ws + 3145728 + 1920000);            //   655,360 B
  float* invS = (float*)(ws + 3145728 + 1920000 + 655360);   //    65,536 B

  pack_wd<<<(NC16 * 3 * 64 + 255) / 256, 256, 0, stream>>>(Wd, Bp);
  lstm_seq<<<B_SZ, 192, 0, stream>>>(z, W, U, b, hsb);
  dense_pass<0><<<512 * NSPLIT, 256, 0, stream>>>(hsb, (const bf16x8*)Bp, bd,
                                                  nullptr, part);
  reduce_inv<<<(NROWS + 255) / 256, 256, 0, stream>>>(part, invS);
  dense_pass<1><<<512 * NSPLIT, 256, 0, stream>>>(hsb, (const bf16x8*)Bp, bd,
                                                  invS, out);
}